// Round 5
// baseline (54.634 us; speedup 1.0000x reference)
//
#include <hip/hip_runtime.h>
#include <hip/hip_bf16.h>

// SimCLR NT-Xent loss v5: 8-wave block (BM=256, 1 block/CU), 4-sub-phase
// interleave per tile (T3) with setprio around MFMA clusters (T5), counted
// vmcnt ring prefetch (T4), M=32 rows/wave, log2-unit defer-max epilogue.

#define NROWS 4096
#define DDIM  512
#define NSPLIT 16                // column splits
#define QCOLS (NROWS / NSPLIT)   // 256 cols per split
#define NT (QCOLS / 16)          // 16 column tiles per block
#define BM 256                   // rows per block (8 waves x 32)
#define NEG_BIG (-3.0e38f)
#define CSCALE 14.4269504088896340736f   // 10 * log2(e): logits in log2 units
#define LN2 0.69314718055994530942f
#define THR 40.0f                // defer-max threshold (log2 units)

typedef __bf16 bf16x8 __attribute__((ext_vector_type(8)));
typedef float  f32x4  __attribute__((ext_vector_type(4)));

#define GLOAD_LDS16(g, l) __builtin_amdgcn_global_load_lds(                    \
    (const __attribute__((address_space(1))) void*)(g),                        \
    (__attribute__((address_space(3))) void*)(l), 16, 0, 0)

#define MFMA16(a, b, c) __builtin_amdgcn_mfma_f32_16x16x32_bf16((a), (b), (c), 0, 0, 0)

// ---------------- kernel 0: fp32 -> bf16 (plain + log2-prescaled) ----------------
__global__ void jl_cvt(const float* __restrict__ in, __bf16* __restrict__ b_out,
                       __bf16* __restrict__ a_out) {
    int i = (blockIdx.x * 256 + threadIdx.x) * 8;
    float4 a = *(const float4*)(in + i);
    float4 b = *(const float4*)(in + i + 4);
    bf16x8 v, w;
    v[0] = (__bf16)a.x; v[1] = (__bf16)a.y; v[2] = (__bf16)a.z; v[3] = (__bf16)a.w;
    v[4] = (__bf16)b.x; v[5] = (__bf16)b.y; v[6] = (__bf16)b.z; v[7] = (__bf16)b.w;
    w[0] = (__bf16)(a.x * CSCALE); w[1] = (__bf16)(a.y * CSCALE);
    w[2] = (__bf16)(a.z * CSCALE); w[3] = (__bf16)(a.w * CSCALE);
    w[4] = (__bf16)(b.x * CSCALE); w[5] = (__bf16)(b.y * CSCALE);
    w[6] = (__bf16)(b.z * CSCALE); w[7] = (__bf16)(b.w * CSCALE);
    *(bf16x8*)(b_out + i) = v;
    *(bf16x8*)(a_out + i) = w;
}

// ---------------- kernel 1: fused GEMM + online log2-sum-exp2 partials ----------------
// grid = (NROWS/BM) * NSPLIT = 16*16 = 256 blocks (1/CU), 512 threads (8 waves).
// block: rows [rbk*256, +256), cols [q*256, +256). wave w: rows [.. + 32w, +32)
__global__ __launch_bounds__(512, 2) void jl_main(const __bf16* __restrict__ ab,
                                                  const __bf16* __restrict__ bb,
                                                  float* __restrict__ pm,
                                                  float* __restrict__ ps,
                                                  float* __restrict__ pos) {
    __shared__ bf16x8 smem[4][16][64];   // 4-buffer ring, fragment-ordered, 64 KB

    const int rbk  = blockIdx.x >> 4;   // 0..15
    const int q    = blockIdx.x & 15;
    const int wave = threadIdx.x >> 6;  // 0..7
    const int lane = threadIdx.x & 63;

    const int row0 = rbk * BM + wave * 32;   // wave's first row (32 rows)
    const int col0 = q * QCOLS;
    const int lrow = lane & 15;
    const int lk   = lane >> 4;

    // A fragments (log2-prescaled), two 16-row halves: 32 x bf16x8 = 128 VGPR
    bf16x8 afA[16], afB[16];
    {
        const __bf16* arow = ab + (size_t)(row0 + lrow) * DDIM + lk * 8;
        #pragma unroll
        for (int kb = 0; kb < 16; ++kb) {
            afA[kb] = *(const bf16x8*)(arow + kb * 32);
            afB[kb] = *(const bf16x8*)(arow + 16 * DDIM + kb * 32);
        }
    }
    #pragma unroll
    for (int kb = 0; kb < 16; ++kb) {
        asm volatile("" : "+v"(afA[kb]));
        asm volatile("" : "+v"(afB[kb]));
    }

    // per-lane fragment-ordered global source for B staging
    const __bf16* gB = bb + (size_t)(col0 + lrow) * DDIM + lk * 8;

    // wave w stages kb = 2w, 2w+1 of each tile (2 gload_lds per wave per tile)
#define STAGE(T)                                                               \
    do {                                                                       \
        const __bf16* g_ = gB + (size_t)(T) * 16 * DDIM;                       \
        _Pragma("unroll")                                                      \
        for (int i_ = 0; i_ < 2; ++i_) {                                       \
            int kb_ = wave * 2 + i_;                                           \
            GLOAD_LDS16(g_ + kb_ * 32, &smem[(T) & 3][kb_][0]);                \
        }                                                                      \
    } while (0)

    STAGE(0);
    STAGE(1);

    float m[2][4], s[2][4];
    #pragma unroll
    for (int h = 0; h < 2; ++h)
        #pragma unroll
        for (int r = 0; r < 4; ++r) { m[h][r] = NEG_BIG; s[h][r] = 0.0f; }

    for (int jt = 0; jt < NT; ++jt) {
        if (jt + 2 < NT) STAGE(jt + 2);

        // counted vmcnt: 2 loads/wave/tile in flight x2 tiles; drain only at tail
        if (jt < NT - 2)       asm volatile("s_waitcnt vmcnt(4)" ::: "memory");
        else if (jt == NT - 2) asm volatile("s_waitcnt vmcnt(2)" ::: "memory");
        else                   asm volatile("s_waitcnt vmcnt(0)" ::: "memory");
        __builtin_amdgcn_s_barrier();
        __builtin_amdgcn_sched_barrier(0);

        const int cb = jt & 3;
        f32x4 accA0 = {0.f,0.f,0.f,0.f}, accA1 = {0.f,0.f,0.f,0.f};
        f32x4 accB0 = {0.f,0.f,0.f,0.f}, accB1 = {0.f,0.f,0.f,0.f};

        // 4 sub-phases: {4x ds_read_b128 -> setprio(1) 8 MFMA setprio(0) -> barrier}
        #pragma unroll
        for (int p = 0; p < 4; ++p) {
            bf16x8 b0 = smem[cb][4 * p + 0][lane];
            bf16x8 b1 = smem[cb][4 * p + 1][lane];
            bf16x8 b2 = smem[cb][4 * p + 2][lane];
            bf16x8 b3 = smem[cb][4 * p + 3][lane];
            __builtin_amdgcn_s_setprio(1);
            accA0 = MFMA16(afA[4 * p + 0], b0, accA0);
            accB0 = MFMA16(afB[4 * p + 0], b0, accB0);
            accA1 = MFMA16(afA[4 * p + 1], b1, accA1);
            accB1 = MFMA16(afB[4 * p + 1], b1, accB1);
            accA0 = MFMA16(afA[4 * p + 2], b2, accA0);
            accB0 = MFMA16(afB[4 * p + 2], b2, accB0);
            accA1 = MFMA16(afA[4 * p + 3], b3, accA1);
            accB1 = MFMA16(afB[4 * p + 3], b3, accB1);
            __builtin_amdgcn_s_setprio(0);
            if (p < 3) {
                __builtin_amdgcn_s_barrier();
                __builtin_amdgcn_sched_barrier(0);
            }
        }

        f32x4 y[2];
        y[0] = accA0 + accA1;   // rows row0    + 4*lk + r, col col0+jt*16+lrow
        y[1] = accB0 + accB1;   // rows row0+16 + 4*lk + r

        const int ctile = col0 + jt * 16;   // wave-uniform

        // positive-pair tiles (uniform, rare): partner of row i is i^2048
        if (ctile == (row0 ^ 2048)) {
            #pragma unroll
            for (int r = 0; r < 4; ++r)
                if (lrow == 4 * lk + r) pos[row0 + 4 * lk + r] = y[0][r];
        }
        if (ctile == ((row0 + 16) ^ 2048)) {
            #pragma unroll
            for (int r = 0; r < 4; ++r)
                if (lrow == 4 * lk + r) pos[row0 + 16 + 4 * lk + r] = y[1][r];
        }

        const bool d0 = (ctile == row0), d1 = (ctile == row0 + 16);
        if (d0 || d1) {
            // diagonal tile (rare): masked full online update
            #pragma unroll
            for (int h = 0; h < 2; ++h) {
                const bool dh = h ? d1 : d0;
                #pragma unroll
                for (int r = 0; r < 4; ++r) {
                    const bool isd = dh && (lrow == 4 * lk + r);
                    float yv = isd ? NEG_BIG : y[h][r];
                    float mn = fmaxf(m[h][r], yv);
                    float e  = isd ? 0.0f : __builtin_amdgcn_exp2f(yv - mn);
                    s[h][r] = s[h][r] * __builtin_amdgcn_exp2f(m[h][r] - mn) + e;
                    m[h][r] = mn;
                }
            }
        } else {
            float t0 = y[0][0] - m[0][0], t1 = y[0][1] - m[0][1];
            float t2 = y[0][2] - m[0][2], t3 = y[0][3] - m[0][3];
            float t4 = y[1][0] - m[1][0], t5 = y[1][1] - m[1][1];
            float t6 = y[1][2] - m[1][2], t7 = y[1][3] - m[1][3];
            float dmax = fmaxf(fmaxf(fmaxf(t0, t1), fmaxf(t2, t3)),
                               fmaxf(fmaxf(t4, t5), fmaxf(t6, t7)));
            if (__any(dmax > THR)) {
                #pragma unroll
                for (int h = 0; h < 2; ++h)
                    #pragma unroll
                    for (int r = 0; r < 4; ++r) {
                        float mn = fmaxf(m[h][r], y[h][r]);
                        s[h][r] = s[h][r] * __builtin_amdgcn_exp2f(m[h][r] - mn)
                                + __builtin_amdgcn_exp2f(y[h][r] - mn);
                        m[h][r] = mn;
                    }
            } else {
                s[0][0] += __builtin_amdgcn_exp2f(t0);
                s[0][1] += __builtin_amdgcn_exp2f(t1);
                s[0][2] += __builtin_amdgcn_exp2f(t2);
                s[0][3] += __builtin_amdgcn_exp2f(t3);
                s[1][0] += __builtin_amdgcn_exp2f(t4);
                s[1][1] += __builtin_amdgcn_exp2f(t5);
                s[1][2] += __builtin_amdgcn_exp2f(t6);
                s[1][3] += __builtin_amdgcn_exp2f(t7);
            }
        }
    }
#undef STAGE

    // merge (m,s) across the 16 lanes of each row group, write partials
    #pragma unroll
    for (int h = 0; h < 2; ++h)
        #pragma unroll
        for (int r = 0; r < 4; ++r) {
            float mm = m[h][r], ss = s[h][r];
            #pragma unroll
            for (int off = 1; off < 16; off <<= 1) {
                float mo = __shfl_xor(mm, off, 64);
                float so = __shfl_xor(ss, off, 64);
                float mn = fmaxf(mm, mo);
                ss = ss * __builtin_amdgcn_exp2f(mm - mn)
                   + so * __builtin_amdgcn_exp2f(mo - mn);
                mm = mn;
            }
            if (lrow == 0) {
                const int grow = row0 + 16 * h + 4 * lk + r;
                pm[grow * NSPLIT + q] = mm;
                ps[grow * NSPLIT + q] = ss;
            }
        }
}

// ---------------- kernel 2: merge partials -> scalar loss ----------------
__global__ void jl_merge(const float* __restrict__ pm, const float* __restrict__ ps,
                         const float* __restrict__ pos, float* __restrict__ out) {
    __shared__ float red[256];
    const int t = threadIdx.x;
    float acc = 0.0f;
    for (int i = t; i < NROWS; i += 256) {
        float mb = NEG_BIG;
        #pragma unroll
        for (int qq = 0; qq < NSPLIT; ++qq) mb = fmaxf(mb, pm[i * NSPLIT + qq]);
        float st = 0.0f;
        #pragma unroll
        for (int qq = 0; qq < NSPLIT; ++qq)
            st += ps[i * NSPLIT + qq] * __builtin_amdgcn_exp2f(pm[i * NSPLIT + qq] - mb);
        // loss_i (nat units) = ln2 * (mb + log2(st) - pos_i)
        acc += mb + __builtin_amdgcn_logf(st) - pos[i];
    }
    red[t] = acc;
    __syncthreads();
    for (int off = 128; off > 0; off >>= 1) {
        if (t < off) red[t] += red[t + off];
        __syncthreads();
    }
    if (t == 0) out[0] = red[0] * (LN2 / (float)NROWS);
}

extern "C" void kernel_launch(void* const* d_in, const int* in_sizes, int n_in,
                              void* d_out, int out_size, void* d_ws, size_t ws_size,
                              hipStream_t stream) {
    const float* rep = (const float*)d_in[0];
    float* out = (float*)d_out;

    // workspace layout: bbuf 4MB | abuf 4MB | pm | ps | pos
    __bf16* bbuf = (__bf16*)d_ws;
    __bf16* abuf = bbuf + (size_t)NROWS * DDIM;
    float*  pm   = (float*)(abuf + (size_t)NROWS * DDIM);
    float*  ps   = pm + NROWS * NSPLIT;
    float*  pos  = ps + NROWS * NSPLIT;

    jl_cvt<<<(NROWS * DDIM) / (256 * 8), 256, 0, stream>>>(rep, bbuf, abuf);
    jl_main<<<(NROWS / BM) * NSPLIT, 512, 0, stream>>>(abuf, bbuf, pm, ps, pos);
    jl_merge<<<1, 256, 0, stream>>>(pm, ps, pos, out);
}

// Round 6
// 48.764 us; speedup vs baseline: 1.1204x; 1.1204x over previous
//
#include <hip/hip_runtime.h>
#include <hip/hip_bf16.h>

// SimCLR NT-Xent loss v6: single sqrt(c)-prescaled bf16 buffer, breg[16]
// full-tile LDS->reg prefetch, 1 barrier/tile + counted vmcnt ring (depth 2),
// setprio around MFMA burst, parallel 2-stage merge.

#define NROWS 4096
#define DDIM  512
#define NSPLIT 16                // column splits
#define QCOLS (NROWS / NSPLIT)   // 256 cols per split
#define NT (QCOLS / 16)          // 16 column tiles per block
#define BM 128                   // rows per block (4 waves x 32)
#define NEG_BIG (-3.0e38f)
#define SQRT_CSCALE 3.798282562f // sqrt(10*log2(e)); (sqrt(c)A)(sqrt(c)B) = c*sim
#define LN2 0.69314718055994530942f
#define THR 40.0f                // defer-max threshold (log2 units)

typedef __bf16 bf16x8 __attribute__((ext_vector_type(8)));
typedef float  f32x4  __attribute__((ext_vector_type(4)));

#define GLOAD_LDS16(g, l) __builtin_amdgcn_global_load_lds(                    \
    (const __attribute__((address_space(1))) void*)(g),                        \
    (__attribute__((address_space(3))) void*)(l), 16, 0, 0)

#define MFMA16(a, b, c) __builtin_amdgcn_mfma_f32_16x16x32_bf16((a), (b), (c), 0, 0, 0)

// ---------------- kernel 0: fp32 -> bf16, scaled by sqrt(c) ----------------
__global__ void jl_cvt(const float* __restrict__ in, __bf16* __restrict__ out) {
    int i = (blockIdx.x * 256 + threadIdx.x) * 8;
    float4 a = *(const float4*)(in + i);
    float4 b = *(const float4*)(in + i + 4);
    bf16x8 w;
    w[0] = (__bf16)(a.x * SQRT_CSCALE); w[1] = (__bf16)(a.y * SQRT_CSCALE);
    w[2] = (__bf16)(a.z * SQRT_CSCALE); w[3] = (__bf16)(a.w * SQRT_CSCALE);
    w[4] = (__bf16)(b.x * SQRT_CSCALE); w[5] = (__bf16)(b.y * SQRT_CSCALE);
    w[6] = (__bf16)(b.z * SQRT_CSCALE); w[7] = (__bf16)(b.w * SQRT_CSCALE);
    *(bf16x8*)(out + i) = w;
}

// ---------------- kernel 1: fused GEMM + online log2-sum-exp2 partials ----------------
// grid = (NROWS/BM) * NSPLIT = 32*16 = 512 blocks (2/CU), 256 threads (4 waves).
// block: rows [rbk*128, +128), cols [q*256, +256). wave w: rows [.. + 32w, +32)
__global__ __launch_bounds__(256, 2) void jl_main(const __bf16* __restrict__ rb,
                                                  float* __restrict__ pm,
                                                  float* __restrict__ ps,
                                                  float* __restrict__ pos) {
    __shared__ bf16x8 smem[4][16][64];   // 4-buffer ring, fragment-ordered, 64 KB

    const int rbk  = blockIdx.x >> 4;   // 0..31
    const int q    = blockIdx.x & 15;
    const int wave = threadIdx.x >> 6;
    const int lane = threadIdx.x & 63;

    const int row0 = rbk * BM + wave * 32;   // wave's first row (32 rows)
    const int col0 = q * QCOLS;
    const int lrow = lane & 15;
    const int lk   = lane >> 4;

    // A fragments, two 16-row halves: 32 x bf16x8 (lives in AGPR, unified file)
    bf16x8 afA[16], afB[16];
    {
        const __bf16* arow = rb + (size_t)(row0 + lrow) * DDIM + lk * 8;
        #pragma unroll
        for (int kb = 0; kb < 16; ++kb) {
            afA[kb] = *(const bf16x8*)(arow + kb * 32);
            afB[kb] = *(const bf16x8*)(arow + 16 * DDIM + kb * 32);
        }
    }

    // per-lane fragment-ordered global source for B staging
    const __bf16* gB = rb + (size_t)(col0 + lrow) * DDIM + lk * 8;

    // wave w stages kb = 4w..4w+3 of each tile (4 gload_lds per wave per tile)
#define STAGE(T)                                                               \
    do {                                                                       \
        const __bf16* g_ = gB + (size_t)(T) * 16 * DDIM;                       \
        _Pragma("unroll")                                                      \
        for (int i_ = 0; i_ < 4; ++i_) {                                       \
            int kb_ = wave * 4 + i_;                                           \
            GLOAD_LDS16(g_ + kb_ * 32, &smem[(T) & 3][kb_][0]);                \
        }                                                                      \
    } while (0)

    STAGE(0);
    STAGE(1);

    float m[2][4], s[2][4];
    #pragma unroll
    for (int h = 0; h < 2; ++h)
        #pragma unroll
        for (int r = 0; r < 4; ++r) { m[h][r] = NEG_BIG; s[h][r] = 0.0f; }

    for (int jt = 0; jt < NT; ++jt) {
        if (jt + 2 < NT) STAGE(jt + 2);

        // counted vmcnt: 4 loads/wave/tile, 2 tiles in flight; drain only at tail
        if (jt < NT - 2)       asm volatile("s_waitcnt vmcnt(8)" ::: "memory");
        else if (jt == NT - 2) asm volatile("s_waitcnt vmcnt(4)" ::: "memory");
        else                   asm volatile("s_waitcnt vmcnt(0)" ::: "memory");
        __builtin_amdgcn_s_barrier();
        __builtin_amdgcn_sched_barrier(0);

        const int cb = jt & 3;

        // full-tile register prefetch: 16 back-to-back ds_read_b128
        bf16x8 breg[16];
        #pragma unroll
        for (int kb = 0; kb < 16; ++kb) breg[kb] = smem[cb][kb][lane];

        f32x4 accA0 = {0.f,0.f,0.f,0.f}, accA1 = {0.f,0.f,0.f,0.f};
        f32x4 accB0 = {0.f,0.f,0.f,0.f}, accB1 = {0.f,0.f,0.f,0.f};
        __builtin_amdgcn_s_setprio(1);
        #pragma unroll
        for (int kb = 0; kb < 16; ++kb) {
            if (kb & 1) {
                accA1 = MFMA16(afA[kb], breg[kb], accA1);
                accB1 = MFMA16(afB[kb], breg[kb], accB1);
            } else {
                accA0 = MFMA16(afA[kb], breg[kb], accA0);
                accB0 = MFMA16(afB[kb], breg[kb], accB0);
            }
        }
        __builtin_amdgcn_s_setprio(0);

        f32x4 y[2];
        y[0] = accA0 + accA1;   // rows row0    + 4*lk + r, col col0+jt*16+lrow
        y[1] = accB0 + accB1;   // rows row0+16 + 4*lk + r

        const int ctile = col0 + jt * 16;   // wave-uniform

        // positive-pair tiles (uniform, rare): partner of row i is i^2048
        if (ctile == (row0 ^ 2048)) {
            #pragma unroll
            for (int r = 0; r < 4; ++r)
                if (lrow == 4 * lk + r) pos[row0 + 4 * lk + r] = y[0][r];
        }
        if (ctile == ((row0 + 16) ^ 2048)) {
            #pragma unroll
            for (int r = 0; r < 4; ++r)
                if (lrow == 4 * lk + r) pos[row0 + 16 + 4 * lk + r] = y[1][r];
        }

        const bool d0 = (ctile == row0), d1 = (ctile == row0 + 16);
        if (d0 || d1) {
            // diagonal tile (rare): masked full online update
            #pragma unroll
            for (int h = 0; h < 2; ++h) {
                const bool dh = h ? d1 : d0;
                #pragma unroll
                for (int r = 0; r < 4; ++r) {
                    const bool isd = dh && (lrow == 4 * lk + r);
                    float yv = isd ? NEG_BIG : y[h][r];
                    float mn = fmaxf(m[h][r], yv);
                    float e  = isd ? 0.0f : __builtin_amdgcn_exp2f(yv - mn);
                    s[h][r] = s[h][r] * __builtin_amdgcn_exp2f(m[h][r] - mn) + e;
                    m[h][r] = mn;
                }
            }
        } else {
            float t0 = y[0][0] - m[0][0], t1 = y[0][1] - m[0][1];
            float t2 = y[0][2] - m[0][2], t3 = y[0][3] - m[0][3];
            float t4 = y[1][0] - m[1][0], t5 = y[1][1] - m[1][1];
            float t6 = y[1][2] - m[1][2], t7 = y[1][3] - m[1][3];
            float dmax = fmaxf(fmaxf(fmaxf(t0, t1), fmaxf(t2, t3)),
                               fmaxf(fmaxf(t4, t5), fmaxf(t6, t7)));
            if (__any(dmax > THR)) {
                #pragma unroll
                for (int h = 0; h < 2; ++h)
                    #pragma unroll
                    for (int r = 0; r < 4; ++r) {
                        float mn = fmaxf(m[h][r], y[h][r]);
                        s[h][r] = s[h][r] * __builtin_amdgcn_exp2f(m[h][r] - mn)
                                + __builtin_amdgcn_exp2f(y[h][r] - mn);
                        m[h][r] = mn;
                    }
            } else {
                s[0][0] += __builtin_amdgcn_exp2f(t0);
                s[0][1] += __builtin_amdgcn_exp2f(t1);
                s[0][2] += __builtin_amdgcn_exp2f(t2);
                s[0][3] += __builtin_amdgcn_exp2f(t3);
                s[1][0] += __builtin_amdgcn_exp2f(t4);
                s[1][1] += __builtin_amdgcn_exp2f(t5);
                s[1][2] += __builtin_amdgcn_exp2f(t6);
                s[1][3] += __builtin_amdgcn_exp2f(t7);
            }
        }
    }
#undef STAGE

    // merge (m,s) across the 16 lanes of each row group, write partials
    #pragma unroll
    for (int h = 0; h < 2; ++h)
        #pragma unroll
        for (int r = 0; r < 4; ++r) {
            float mm = m[h][r], ss = s[h][r];
            #pragma unroll
            for (int off = 1; off < 16; off <<= 1) {
                float mo = __shfl_xor(mm, off, 64);
                float so = __shfl_xor(ss, off, 64);
                float mn = fmaxf(mm, mo);
                ss = ss * __builtin_amdgcn_exp2f(mm - mn)
                   + so * __builtin_amdgcn_exp2f(mo - mn);
                mm = mn;
            }
            if (lrow == 0) {
                const int grow = row0 + 16 * h + 4 * lk + r;
                pm[grow * NSPLIT + q] = mm;
                ps[grow * NSPLIT + q] = ss;
            }
        }
}

// ---------------- kernel 2a: per-row loss + per-block partial sum ----------------
__global__ void jl_rowloss(const float* __restrict__ pm, const float* __restrict__ ps,
                           const float* __restrict__ pos, float* __restrict__ part) {
    __shared__ float red[256];
    const int t = threadIdx.x;
    const int row = blockIdx.x * 256 + t;
    float mb = NEG_BIG;
    #pragma unroll
    for (int qq = 0; qq < NSPLIT; ++qq) mb = fmaxf(mb, pm[row * NSPLIT + qq]);
    float st = 0.0f;
    #pragma unroll
    for (int qq = 0; qq < NSPLIT; ++qq)
        st += ps[row * NSPLIT + qq] * __builtin_amdgcn_exp2f(pm[row * NSPLIT + qq] - mb);
    // per-row loss in log2 units: mb + log2(st) - pos
    red[t] = mb + __builtin_amdgcn_logf(st) - pos[row];
    __syncthreads();
    for (int off = 128; off > 0; off >>= 1) {
        if (t < off) red[t] += red[t + off];
        __syncthreads();
    }
    if (t == 0) part[blockIdx.x] = red[0];
}

// ---------------- kernel 2b: final reduce ----------------
__global__ void jl_final(const float* __restrict__ part, float* __restrict__ out) {
    const int t = threadIdx.x;
    float v = (t < NROWS / 256) ? part[t] : 0.0f;
    #pragma unroll
    for (int off = 1; off < 16; off <<= 1) v += __shfl_xor(v, off, 64);
    if (t == 0) out[0] = v * (LN2 / (float)NROWS);
}

extern "C" void kernel_launch(void* const* d_in, const int* in_sizes, int n_in,
                              void* d_out, int out_size, void* d_ws, size_t ws_size,
                              hipStream_t stream) {
    const float* rep = (const float*)d_in[0];
    float* out = (float*)d_out;

    // workspace layout: rbuf 4MB | pm | ps | pos | part
    __bf16* rbuf = (__bf16*)d_ws;
    float*  pm   = (float*)(rbuf + (size_t)NROWS * DDIM);
    float*  ps   = pm + NROWS * NSPLIT;
    float*  pos  = ps + NROWS * NSPLIT;
    float*  part = pos + NROWS;

    jl_cvt<<<(NROWS * DDIM) / (256 * 8), 256, 0, stream>>>(rep, rbuf);
    jl_main<<<(NROWS / BM) * NSPLIT, 256, 0, stream>>>(rbuf, pm, ps, pos);
    jl_rowloss<<<NROWS / 256, 256, 0, stream>>>(pm, ps, pos, part);
    jl_final<<<1, 64, 0, stream>>>(part, out);
}